// Round 13
// baseline (90.201 us; speedup 1.0000x reference)
//
#include <hip/hip_runtime.h>

#define NG  512
#define GW  32768    // G*W
#define GH3 32768    // G*H3

typedef __attribute__((ext_vector_type(8))) short bf16x8;
typedef __attribute__((ext_vector_type(4))) float f32x4;
typedef __attribute__((ext_vector_type(4))) unsigned int u32x4;
typedef __attribute__((ext_vector_type(2))) __bf16 bf16x2;

union frag_u { u32x4 u; bf16x8 h; };

#define MFMA __builtin_amdgcn_mfma_f32_16x16x32_bf16

// two floats -> packed bf16 pair (RNE); clang fuses into v_cvt_pk_bf16_f32
__device__ __forceinline__ unsigned cvt2bf(float a, float b) {
  bf16x2 v = {(__bf16)a, (__bf16)b};
  return __builtin_bit_cast(unsigned, v);
}

// (E,O) packed D-words -> B-operand words via half/row swaps.
__device__ __forceinline__ void permswap(unsigned &e, unsigned &o) {
  asm volatile("s_nop 1\n\t"
               "v_permlane32_swap_b32 %0, %1\n\t"
               "s_nop 1\n\t"
               "v_permlane16_swap_b32 %0, %1\n\t"
               "s_nop 1"
               : "+v"(e), "+v"(o));
}

// One B-fragment from an acc-tile pair, with relu.
__device__ __forceinline__ void mk_bfrag1(f32x4 e, f32x4 o, frag_u &bf) {
  unsigned E0 = cvt2bf(fmaxf(e[0], 0.f), fmaxf(e[1], 0.f));
  unsigned E1 = cvt2bf(fmaxf(e[2], 0.f), fmaxf(e[3], 0.f));
  unsigned O0 = cvt2bf(fmaxf(o[0], 0.f), fmaxf(o[1], 0.f));
  unsigned O1 = cvt2bf(fmaxf(o[2], 0.f), fmaxf(o[3], 0.f));
  permswap(E0, O0);   // -> w0, w2
  permswap(E1, O1);   // -> w1, w3
  bf.u = (u32x4){E0, E1, O0, O1};
}

// Stage W[g] ([K][H] fp32 row-major) into LDS frag-major (conflict-free).
// W is touch-once -> non-temporal loads (no L2/L3 allocation).
template<int K, int H>
__device__ __forceinline__ void stage_frag(const float* __restrict__ gsrc,
                                           char* ldsBase, int tid) {
  constexpr int KC = K / 32;
  constexpr int NELEM = (K / 8) * H;
  #pragma unroll
  for (int lin = tid; lin < NELEM; lin += 512) {
    const int h  = lin & (H - 1);
    const int kb = lin / H;
    const float* p = gsrc + h + (size_t)(8 * kb) * H;
    unsigned w0 = cvt2bf(__builtin_nontemporal_load(p + 0 * H),
                         __builtin_nontemporal_load(p + 1 * H));
    unsigned w1 = cvt2bf(__builtin_nontemporal_load(p + 2 * H),
                         __builtin_nontemporal_load(p + 3 * H));
    unsigned w2 = cvt2bf(__builtin_nontemporal_load(p + 4 * H),
                         __builtin_nontemporal_load(p + 5 * H));
    unsigned w3 = cvt2bf(__builtin_nontemporal_load(p + 6 * H),
                         __builtin_nontemporal_load(p + 7 * H));
    const int mt = h >> 4, bl = h & 15, kc = kb >> 2, bq = kb & 3;
    const int byteoff = ((mt * KC + kc) * 64 + bq * 16 + bl) * 16;
    *(u32x4*)(ldsBase + byteoff) = (u32x4){w0, w1, w2, w3};
  }
}

// Raw x row segment, non-temporal (x is touch-once).
__device__ __forceinline__ void ld_raw(const float* px, f32x4* d) {
  d[0] = __builtin_nontemporal_load((const f32x4*)(px + 0));
  d[1] = __builtin_nontemporal_load((const f32x4*)(px + 4));
  d[2] = __builtin_nontemporal_load((const f32x4*)(px + 32));
  d[3] = __builtin_nontemporal_load((const f32x4*)(px + 36));
}

__device__ __forceinline__ void cvt_b1(const f32x4* d, frag_u* b1) {
  b1[0].u = (u32x4){cvt2bf(d[0][0], d[0][1]), cvt2bf(d[0][2], d[0][3]),
                    cvt2bf(d[1][0], d[1][1]), cvt2bf(d[1][2], d[1][3])};
  b1[1].u = (u32x4){cvt2bf(d[2][0], d[2][1]), cvt2bf(d[2][2], d[2][3]),
                    cvt2bf(d[3][0], d[3][1]), cvt2bf(d[3][2], d[3][3])};
}

// r8 geometry (best 70.8us): 512 thr, 2 blk/CU, 4 waves/SIMD.
__global__ __launch_bounds__(512, 4)
void DeepBlockDense_kernel(const float* __restrict__ x,
                           const float* __restrict__ w1,
                           const float* __restrict__ w2,
                           const float* __restrict__ w3,
                           float* __restrict__ out) {
  __shared__ __align__(16) char smem[65536];
  // T1 XCD-chunked swizzle (free; co-present in best result).
  const int g    = ((blockIdx.x & 7) << 6) + (blockIdx.x >> 3);
  const int tid  = threadIdx.x;
  const int lane = tid & 63;
  const int wid  = tid >> 6;
  const int bq   = lane >> 4;

  const float* xbase = x + g * 64 + 8 * bq + (size_t)(wid * 16 + (lane & 15)) * GW;

  // T14: issue t=0 x-loads BEFORE staging (hide under stage phase)
  f32x4 xra[4], xrb[4];
  ld_raw(xbase + (size_t)0   * GW, xra);
  ld_raw(xbase + (size_t)128 * GW, xrb);

  stage_frag<64 , 128>(w1 + (size_t)g * (64 * 128) , smem        , tid);
  stage_frag<128, 128>(w2 + (size_t)g * (128 * 128), smem + 16384, tid);
  stage_frag<128, 64 >(w3 + (size_t)g * (128 * 64) , smem + 49152, tid);
  __syncthreads();

  const char* aBase = smem + lane * 16;   // frags at compile-time imm offsets

  #pragma unroll 1
  for (int t = 0; t < 4; ++t) {
    const size_t r0 = (size_t)(t * 256 + wid * 16 + (lane & 15));
    const size_t r1 = r0 + 128;

    // ---- consume prefetched x; immediately issue next iter's loads
    frag_u b1a[2], b1b[2];
    cvt_b1(xra, b1a);
    cvt_b1(xrb, b1b);
    if (t < 3) {
      ld_raw(xbase + (size_t)(t * 256 + 256) * GW, xra);
      ld_raw(xbase + (size_t)(t * 256 + 384) * GW, xrb);
    }

    // ---- layer 1 (M=128,K=64), interleaved with b2-frag build per mt-pair
    frag_u b2a[4], b2b[4];
    #pragma unroll
    for (int pr = 0; pr < 4; ++pr) {
      f32x4 ea = {}, oa = {}, eb = {}, ob = {};
      #pragma unroll
      for (int kc = 0; kc < 2; ++kc) {
        frag_u ae, ao;
        ae.u = *(const u32x4*)(aBase + 1024 * ((2 * pr    ) * 2 + kc));
        ao.u = *(const u32x4*)(aBase + 1024 * ((2 * pr + 1) * 2 + kc));
        ea = MFMA(ae.h, b1a[kc].h, ea, 0, 0, 0);
        eb = MFMA(ae.h, b1b[kc].h, eb, 0, 0, 0);
        oa = MFMA(ao.h, b1a[kc].h, oa, 0, 0, 0);
        ob = MFMA(ao.h, b1b[kc].h, ob, 0, 0, 0);
      }
      mk_bfrag1(ea, oa, b2a[pr]);
      mk_bfrag1(eb, ob, b2b[pr]);
    }

    // ---- layer 2 (M=128,K=128) + layer 3 (M=64,K=128) interleaved per mt-pair
    f32x4 acc3a[4] = {}, acc3b[4] = {};
    #pragma unroll
    for (int pr = 0; pr < 4; ++pr) {
      f32x4 ea = {}, oa = {}, eb = {}, ob = {};
      #pragma unroll
      for (int kc = 0; kc < 4; ++kc) {
        frag_u ae, ao;
        ae.u = *(const u32x4*)(aBase + 16384 + 1024 * ((2 * pr    ) * 4 + kc));
        ao.u = *(const u32x4*)(aBase + 16384 + 1024 * ((2 * pr + 1) * 4 + kc));
        ea = MFMA(ae.h, b2a[kc].h, ea, 0, 0, 0);
        eb = MFMA(ae.h, b2b[kc].h, eb, 0, 0, 0);
        oa = MFMA(ao.h, b2a[kc].h, oa, 0, 0, 0);
        ob = MFMA(ao.h, b2b[kc].h, ob, 0, 0, 0);
      }
      frag_u b3a, b3b;
      mk_bfrag1(ea, oa, b3a);
      mk_bfrag1(eb, ob, b3b);
      #pragma unroll
      for (int mt = 0; mt < 4; ++mt) {
        frag_u a;
        a.u = *(const u32x4*)(aBase + 49152 + 1024 * (mt * 4 + pr));
        acc3a[mt] = MFMA(a.h, b3a.h, acc3a[mt], 0, 0, 0);
        acc3b[mt] = MFMA(a.h, b3b.h, acc3b[mt], 0, 0, 0);
      }
    }

    // ---- relu + NT stores (out is touch-once too)
    float* po0 = out + r0 * GH3 + g * 64 + 4 * bq;
    float* po1 = out + r1 * GH3 + g * 64 + 4 * bq;
    #pragma unroll
    for (int mt = 0; mt < 4; ++mt) {
      f32x4 va = acc3a[mt];
      va[0] = fmaxf(va[0], 0.f); va[1] = fmaxf(va[1], 0.f);
      va[2] = fmaxf(va[2], 0.f); va[3] = fmaxf(va[3], 0.f);
      __builtin_nontemporal_store(va, (f32x4*)(po0 + 16 * mt));
    }
    #pragma unroll
    for (int mt = 0; mt < 4; ++mt) {
      f32x4 vb = acc3b[mt];
      vb[0] = fmaxf(vb[0], 0.f); vb[1] = fmaxf(vb[1], 0.f);
      vb[2] = fmaxf(vb[2], 0.f); vb[3] = fmaxf(vb[3], 0.f);
      __builtin_nontemporal_store(vb, (f32x4*)(po1 + 16 * mt));
    }
  }
}

extern "C" void kernel_launch(void* const* d_in, const int* in_sizes, int n_in,
                              void* d_out, int out_size, void* d_ws, size_t ws_size,
                              hipStream_t stream) {
  const float* x  = (const float*)d_in[0];
  const float* w1 = (const float*)d_in[1];
  const float* w2 = (const float*)d_in[2];
  const float* w3 = (const float*)d_in[3];
  float* out = (float*)d_out;
  (void)in_sizes; (void)n_in; (void)out_size; (void)d_ws; (void)ws_size;
  DeepBlockDense_kernel<<<dim3(NG), dim3(512), 0, stream>>>(x, w1, w2, w3, out);
}

// Round 14
// 71.977 us; speedup vs baseline: 1.2532x; 1.2532x over previous
//
#include <hip/hip_runtime.h>

#define NG  512
#define GW  32768    // G*W
#define GH3 32768    // G*H3

typedef __attribute__((ext_vector_type(8))) short bf16x8;
typedef __attribute__((ext_vector_type(4))) float f32x4;
typedef __attribute__((ext_vector_type(4))) unsigned int u32x4;
typedef __attribute__((ext_vector_type(2))) __bf16 bf16x2;

union frag_u { u32x4 u; bf16x8 h; };

#define MFMA __builtin_amdgcn_mfma_f32_16x16x32_bf16

// two floats -> packed bf16 pair (RNE); clang fuses into v_cvt_pk_bf16_f32
__device__ __forceinline__ unsigned cvt2bf(float a, float b) {
  bf16x2 v = {(__bf16)a, (__bf16)b};
  return __builtin_bit_cast(unsigned, v);
}

// (E,O) packed D-words -> B-operand words via half/row swaps.
__device__ __forceinline__ void permswap(unsigned &e, unsigned &o) {
  asm volatile("s_nop 1\n\t"
               "v_permlane32_swap_b32 %0, %1\n\t"
               "s_nop 1\n\t"
               "v_permlane16_swap_b32 %0, %1\n\t"
               "s_nop 1"
               : "+v"(e), "+v"(o));
}

// One B-fragment from an acc-tile pair, with relu.
__device__ __forceinline__ void mk_bfrag1(f32x4 e, f32x4 o, frag_u &bf) {
  unsigned E0 = cvt2bf(fmaxf(e[0], 0.f), fmaxf(e[1], 0.f));
  unsigned E1 = cvt2bf(fmaxf(e[2], 0.f), fmaxf(e[3], 0.f));
  unsigned O0 = cvt2bf(fmaxf(o[0], 0.f), fmaxf(o[1], 0.f));
  unsigned O1 = cvt2bf(fmaxf(o[2], 0.f), fmaxf(o[3], 0.f));
  permswap(E0, O0);   // -> w0, w2
  permswap(E1, O1);   // -> w1, w3
  bf.u = (u32x4){E0, E1, O0, O1};
}

// Stage W[g] ([K][H] fp32 row-major) into LDS frag-major (conflict-free),
// VECTORIZED: f32x4 along contiguous h -> 16 dwordx4/thread instead of
// 64 scalar dwords. Each (kb,h4) iter: 8 f32x4 loads (1KB/wave-instr
// coalesced), 4 b128 LDS writes at +0/16/32/48 of the same frag.
template<int K, int H>
__device__ __forceinline__ void stage_frag(const float* __restrict__ gsrc,
                                           char* ldsBase, int tid) {
  constexpr int KC = K / 32;
  constexpr int H4 = H / 4;
  constexpr int NELEM4 = (K / 8) * H4;
  #pragma unroll
  for (int lin = tid; lin < NELEM4; lin += 512) {
    const int h4 = lin & (H4 - 1);
    const int kb = lin / H4;
    const int h  = 4 * h4;
    const float* p = gsrc + (size_t)(8 * kb) * H + h;
    f32x4 v[8];
    #pragma unroll
    for (int j = 0; j < 8; ++j) v[j] = *(const f32x4*)(p + j * H);
    const int mt = h >> 4, bl = h & 15, kc = kb >> 2, bq = kb & 3;
    const int base = ((mt * KC + kc) * 64 + bq * 16 + bl) * 16;
    #pragma unroll
    for (int dh = 0; dh < 4; ++dh) {
      u32x4 w = (u32x4){cvt2bf(v[0][dh], v[1][dh]), cvt2bf(v[2][dh], v[3][dh]),
                        cvt2bf(v[4][dh], v[5][dh]), cvt2bf(v[6][dh], v[7][dh])};
      *(u32x4*)(ldsBase + base + 16 * dh) = w;
    }
  }
}

// Raw x row segment: 4 f32x4 (k-octets bq and bq+4). PLAIN loads
// (r13: NT loads destructive when combined with NT stores).
__device__ __forceinline__ void ld_raw(const float* px, f32x4* d) {
  d[0] = *(const f32x4*)(px + 0);
  d[1] = *(const f32x4*)(px + 4);
  d[2] = *(const f32x4*)(px + 32);
  d[3] = *(const f32x4*)(px + 36);
}

__device__ __forceinline__ void cvt_b1(const f32x4* d, frag_u* b1) {
  b1[0].u = (u32x4){cvt2bf(d[0][0], d[0][1]), cvt2bf(d[0][2], d[0][3]),
                    cvt2bf(d[1][0], d[1][1]), cvt2bf(d[1][2], d[1][3])};
  b1[1].u = (u32x4){cvt2bf(d[2][0], d[2][1]), cvt2bf(d[2][2], d[2][3]),
                    cvt2bf(d[3][0], d[3][1]), cvt2bf(d[3][2], d[3][3])};
}

// r8 geometry (best 70.8us): 512 thr, 2 blk/CU, 4 waves/SIMD.
__global__ __launch_bounds__(512, 4)
void DeepBlockDense_kernel(const float* __restrict__ x,
                           const float* __restrict__ w1,
                           const float* __restrict__ w2,
                           const float* __restrict__ w3,
                           float* __restrict__ out) {
  __shared__ __align__(16) char smem[65536];
  // T1 XCD-chunked swizzle (free; co-present in best result).
  const int g    = ((blockIdx.x & 7) << 6) + (blockIdx.x >> 3);
  const int tid  = threadIdx.x;
  const int lane = tid & 63;
  const int wid  = tid >> 6;
  const int bq   = lane >> 4;

  const float* xbase = x + g * 64 + 8 * bq + (size_t)(wid * 16 + (lane & 15)) * GW;

  // T14: issue t=0 x-loads BEFORE staging (hide under stage phase)
  f32x4 xra[4], xrb[4];
  ld_raw(xbase + (size_t)0   * GW, xra);
  ld_raw(xbase + (size_t)128 * GW, xrb);

  stage_frag<64 , 128>(w1 + (size_t)g * (64 * 128) , smem        , tid);
  stage_frag<128, 128>(w2 + (size_t)g * (128 * 128), smem + 16384, tid);
  stage_frag<128, 64 >(w3 + (size_t)g * (128 * 64) , smem + 49152, tid);
  __syncthreads();

  const char* aBase = smem + lane * 16;   // frags at compile-time imm offsets

  #pragma unroll 1
  for (int t = 0; t < 4; ++t) {
    const size_t r0 = (size_t)(t * 256 + wid * 16 + (lane & 15));
    const size_t r1 = r0 + 128;

    // ---- consume prefetched x; immediately issue next iter's loads
    frag_u b1a[2], b1b[2];
    cvt_b1(xra, b1a);
    cvt_b1(xrb, b1b);
    if (t < 3) {
      ld_raw(xbase + (size_t)(t * 256 + 256) * GW, xra);
      ld_raw(xbase + (size_t)(t * 256 + 384) * GW, xrb);
    }

    // ---- layer 1 (M=128,K=64), interleaved with b2-frag build per mt-pair
    frag_u b2a[4], b2b[4];
    #pragma unroll
    for (int pr = 0; pr < 4; ++pr) {
      f32x4 ea = {}, oa = {}, eb = {}, ob = {};
      #pragma unroll
      for (int kc = 0; kc < 2; ++kc) {
        frag_u ae, ao;
        ae.u = *(const u32x4*)(aBase + 1024 * ((2 * pr    ) * 2 + kc));
        ao.u = *(const u32x4*)(aBase + 1024 * ((2 * pr + 1) * 2 + kc));
        ea = MFMA(ae.h, b1a[kc].h, ea, 0, 0, 0);
        eb = MFMA(ae.h, b1b[kc].h, eb, 0, 0, 0);
        oa = MFMA(ao.h, b1a[kc].h, oa, 0, 0, 0);
        ob = MFMA(ao.h, b1b[kc].h, ob, 0, 0, 0);
      }
      mk_bfrag1(ea, oa, b2a[pr]);
      mk_bfrag1(eb, ob, b2b[pr]);
    }

    // ---- layer 2 (M=128,K=128) + layer 3 (M=64,K=128) interleaved per mt-pair
    f32x4 acc3a[4] = {}, acc3b[4] = {};
    #pragma unroll
    for (int pr = 0; pr < 4; ++pr) {
      f32x4 ea = {}, oa = {}, eb = {}, ob = {};
      #pragma unroll
      for (int kc = 0; kc < 4; ++kc) {
        frag_u ae, ao;
        ae.u = *(const u32x4*)(aBase + 16384 + 1024 * ((2 * pr    ) * 4 + kc));
        ao.u = *(const u32x4*)(aBase + 16384 + 1024 * ((2 * pr + 1) * 4 + kc));
        ea = MFMA(ae.h, b2a[kc].h, ea, 0, 0, 0);
        eb = MFMA(ae.h, b2b[kc].h, eb, 0, 0, 0);
        oa = MFMA(ao.h, b2a[kc].h, oa, 0, 0, 0);
        ob = MFMA(ao.h, b2b[kc].h, ob, 0, 0, 0);
      }
      frag_u b3a, b3b;
      mk_bfrag1(ea, oa, b3a);
      mk_bfrag1(eb, ob, b3b);
      #pragma unroll
      for (int mt = 0; mt < 4; ++mt) {
        frag_u a;
        a.u = *(const u32x4*)(aBase + 49152 + 1024 * (mt * 4 + pr));
        acc3a[mt] = MFMA(a.h, b3a.h, acc3a[mt], 0, 0, 0);
        acc3b[mt] = MFMA(a.h, b3b.h, acc3b[mt], 0, 0, 0);
      }
    }

    // ---- relu + NT stores (r8 optimum: plain loads + NT stores)
    float* po0 = out + r0 * GH3 + g * 64 + 4 * bq;
    float* po1 = out + r1 * GH3 + g * 64 + 4 * bq;
    #pragma unroll
    for (int mt = 0; mt < 4; ++mt) {
      f32x4 va = acc3a[mt];
      va[0] = fmaxf(va[0], 0.f); va[1] = fmaxf(va[1], 0.f);
      va[2] = fmaxf(va[2], 0.f); va[3] = fmaxf(va[3], 0.f);
      __builtin_nontemporal_store(va, (f32x4*)(po0 + 16 * mt));
    }
    #pragma unroll
    for (int mt = 0; mt < 4; ++mt) {
      f32x4 vb = acc3b[mt];
      vb[0] = fmaxf(vb[0], 0.f); vb[1] = fmaxf(vb[1], 0.f);
      vb[2] = fmaxf(vb[2], 0.f); vb[3] = fmaxf(vb[3], 0.f);
      __builtin_nontemporal_store(vb, (f32x4*)(po1 + 16 * mt));
    }
  }
}

extern "C" void kernel_launch(void* const* d_in, const int* in_sizes, int n_in,
                              void* d_out, int out_size, void* d_ws, size_t ws_size,
                              hipStream_t stream) {
  const float* x  = (const float*)d_in[0];
  const float* w1 = (const float*)d_in[1];
  const float* w2 = (const float*)d_in[2];
  const float* w3 = (const float*)d_in[3];
  float* out = (float*)d_out;
  (void)in_sizes; (void)n_in; (void)out_size; (void)d_ws; (void)ws_size;
  DeepBlockDense_kernel<<<dim3(NG), dim3(512), 0, stream>>>(x, w1, w2, w3, out);
}

// Round 15
// 71.151 us; speedup vs baseline: 1.2677x; 1.0116x over previous
//
#include <hip/hip_runtime.h>

#define NG  512
#define GW  32768    // G*W
#define GH3 32768    // G*H3

typedef __attribute__((ext_vector_type(8))) short bf16x8;
typedef __attribute__((ext_vector_type(4))) float f32x4;
typedef __attribute__((ext_vector_type(4))) unsigned int u32x4;
typedef __attribute__((ext_vector_type(2))) __bf16 bf16x2;

union frag_u { u32x4 u; bf16x8 h; };

#define MFMA __builtin_amdgcn_mfma_f32_16x16x32_bf16

// two floats -> packed bf16 pair (RNE); clang fuses into v_cvt_pk_bf16_f32
__device__ __forceinline__ unsigned cvt2bf(float a, float b) {
  bf16x2 v = {(__bf16)a, (__bf16)b};
  return __builtin_bit_cast(unsigned, v);
}

// (E,O) packed D-words -> B-operand words via half/row swaps.
__device__ __forceinline__ void permswap(unsigned &e, unsigned &o) {
  asm volatile("s_nop 1\n\t"
               "v_permlane32_swap_b32 %0, %1\n\t"
               "s_nop 1\n\t"
               "v_permlane16_swap_b32 %0, %1\n\t"
               "s_nop 1"
               : "+v"(e), "+v"(o));
}

// One B-fragment from an acc-tile pair, with relu.
__device__ __forceinline__ void mk_bfrag1(f32x4 e, f32x4 o, frag_u &bf) {
  unsigned E0 = cvt2bf(fmaxf(e[0], 0.f), fmaxf(e[1], 0.f));
  unsigned E1 = cvt2bf(fmaxf(e[2], 0.f), fmaxf(e[3], 0.f));
  unsigned O0 = cvt2bf(fmaxf(o[0], 0.f), fmaxf(o[1], 0.f));
  unsigned O1 = cvt2bf(fmaxf(o[2], 0.f), fmaxf(o[3], 0.f));
  permswap(E0, O0);   // -> w0, w2
  permswap(E1, O1);   // -> w1, w3
  bf.u = (u32x4){E0, E1, O0, O1};
}

// Stage W[g] ([K][H] fp32 row-major) into LDS frag-major (conflict-free):
// frag (mt,kc) = 1024 contiguous bytes, lane slot at lane*16.
// Scalar loads: r14 showed vectorizing this is null (staging is hidden)
// and adds LDS write conflicts.
template<int K, int H>
__device__ __forceinline__ void stage_frag(const float* __restrict__ gsrc,
                                           char* ldsBase, int tid) {
  constexpr int KC = K / 32;
  constexpr int NELEM = (K / 8) * H;
  #pragma unroll
  for (int lin = tid; lin < NELEM; lin += 512) {
    const int h  = lin & (H - 1);
    const int kb = lin / H;
    const float* p = gsrc + h + (size_t)(8 * kb) * H;
    unsigned w0 = cvt2bf(p[0 * H], p[1 * H]);
    unsigned w1 = cvt2bf(p[2 * H], p[3 * H]);
    unsigned w2 = cvt2bf(p[4 * H], p[5 * H]);
    unsigned w3 = cvt2bf(p[6 * H], p[7 * H]);
    const int mt = h >> 4, bl = h & 15, kc = kb >> 2, bq = kb & 3;
    const int byteoff = ((mt * KC + kc) * 64 + bq * 16 + bl) * 16;
    *(u32x4*)(ldsBase + byteoff) = (u32x4){w0, w1, w2, w3};
  }
}

// Raw x row segment: 4 f32x4 (k-octets bq and bq+4). PLAIN loads
// (L2/L3 read assist is beneficial; NT loads lose when paired with NT stores).
__device__ __forceinline__ void ld_raw(const float* px, f32x4* d) {
  d[0] = *(const f32x4*)(px + 0);
  d[1] = *(const f32x4*)(px + 4);
  d[2] = *(const f32x4*)(px + 32);
  d[3] = *(const f32x4*)(px + 36);
}

__device__ __forceinline__ void cvt_b1(const f32x4* d, frag_u* b1) {
  b1[0].u = (u32x4){cvt2bf(d[0][0], d[0][1]), cvt2bf(d[0][2], d[0][3]),
                    cvt2bf(d[1][0], d[1][1]), cvt2bf(d[1][2], d[1][3])};
  b1[1].u = (u32x4){cvt2bf(d[2][0], d[2][1]), cvt2bf(d[2][2], d[2][3]),
                    cvt2bf(d[3][0], d[3][1]), cvt2bf(d[3][2], d[3][3])};
}

// Best measured configuration (r8: 70.8us): 512 thr, 2 blk/CU, 4 waves/SIMD,
// plain x loads + 1-iter prefetch, NT stores, XCD-chunked swizzle.
__global__ __launch_bounds__(512, 4)
void DeepBlockDense_kernel(const float* __restrict__ x,
                           const float* __restrict__ w1,
                           const float* __restrict__ w2,
                           const float* __restrict__ w3,
                           float* __restrict__ out) {
  __shared__ __align__(16) char smem[65536];
  // T1 XCD-chunked swizzle: XCD k owns groups [k*64,(k+1)*64) -> each XCD
  // touches a contiguous 16-KB span of every x/out row.
  const int g    = ((blockIdx.x & 7) << 6) + (blockIdx.x >> 3);
  const int tid  = threadIdx.x;
  const int lane = tid & 63;
  const int wid  = tid >> 6;
  const int bq   = lane >> 4;

  const float* xbase = x + g * 64 + 8 * bq + (size_t)(wid * 16 + (lane & 15)) * GW;

  // T14: issue t=0 x-loads BEFORE staging (hide under stage phase)
  f32x4 xra[4], xrb[4];
  ld_raw(xbase + (size_t)0   * GW, xra);
  ld_raw(xbase + (size_t)128 * GW, xrb);

  stage_frag<64 , 128>(w1 + (size_t)g * (64 * 128) , smem        , tid);
  stage_frag<128, 128>(w2 + (size_t)g * (128 * 128), smem + 16384, tid);
  stage_frag<128, 64 >(w3 + (size_t)g * (128 * 64) , smem + 49152, tid);
  __syncthreads();

  const char* aBase = smem + lane * 16;   // frags at compile-time imm offsets

  #pragma unroll 1
  for (int t = 0; t < 4; ++t) {
    const size_t r0 = (size_t)(t * 256 + wid * 16 + (lane & 15));
    const size_t r1 = r0 + 128;

    // ---- consume prefetched x; immediately issue next iter's loads
    frag_u b1a[2], b1b[2];
    cvt_b1(xra, b1a);
    cvt_b1(xrb, b1b);
    if (t < 3) {
      ld_raw(xbase + (size_t)(t * 256 + 256) * GW, xra);
      ld_raw(xbase + (size_t)(t * 256 + 384) * GW, xrb);
    }

    // ---- layer 1 (M=128,K=64), interleaved with b2-frag build per mt-pair
    frag_u b2a[4], b2b[4];
    #pragma unroll
    for (int pr = 0; pr < 4; ++pr) {
      f32x4 ea = {}, oa = {}, eb = {}, ob = {};
      #pragma unroll
      for (int kc = 0; kc < 2; ++kc) {
        frag_u ae, ao;
        ae.u = *(const u32x4*)(aBase + 1024 * ((2 * pr    ) * 2 + kc));
        ao.u = *(const u32x4*)(aBase + 1024 * ((2 * pr + 1) * 2 + kc));
        ea = MFMA(ae.h, b1a[kc].h, ea, 0, 0, 0);
        eb = MFMA(ae.h, b1b[kc].h, eb, 0, 0, 0);
        oa = MFMA(ao.h, b1a[kc].h, oa, 0, 0, 0);
        ob = MFMA(ao.h, b1b[kc].h, ob, 0, 0, 0);
      }
      mk_bfrag1(ea, oa, b2a[pr]);
      mk_bfrag1(eb, ob, b2b[pr]);
    }

    // ---- layer 2 (M=128,K=128) + layer 3 (M=64,K=128) interleaved per mt-pair
    f32x4 acc3a[4] = {}, acc3b[4] = {};
    #pragma unroll
    for (int pr = 0; pr < 4; ++pr) {
      f32x4 ea = {}, oa = {}, eb = {}, ob = {};
      #pragma unroll
      for (int kc = 0; kc < 4; ++kc) {
        frag_u ae, ao;
        ae.u = *(const u32x4*)(aBase + 16384 + 1024 * ((2 * pr    ) * 4 + kc));
        ao.u = *(const u32x4*)(aBase + 16384 + 1024 * ((2 * pr + 1) * 4 + kc));
        ea = MFMA(ae.h, b2a[kc].h, ea, 0, 0, 0);
        eb = MFMA(ae.h, b2b[kc].h, eb, 0, 0, 0);
        oa = MFMA(ao.h, b2a[kc].h, oa, 0, 0, 0);
        ob = MFMA(ao.h, b2b[kc].h, ob, 0, 0, 0);
      }
      frag_u b3a, b3b;
      mk_bfrag1(ea, oa, b3a);
      mk_bfrag1(eb, ob, b3b);
      #pragma unroll
      for (int mt = 0; mt < 4; ++mt) {
        frag_u a;
        a.u = *(const u32x4*)(aBase + 49152 + 1024 * (mt * 4 + pr));
        acc3a[mt] = MFMA(a.h, b3a.h, acc3a[mt], 0, 0, 0);
        acc3b[mt] = MFMA(a.h, b3b.h, acc3b[mt], 0, 0, 0);
      }
    }

    // ---- relu + NT stores (the one big win: -13us, L2 write-allocate relief)
    float* po0 = out + r0 * GH3 + g * 64 + 4 * bq;
    float* po1 = out + r1 * GH3 + g * 64 + 4 * bq;
    #pragma unroll
    for (int mt = 0; mt < 4; ++mt) {
      f32x4 va = acc3a[mt];
      va[0] = fmaxf(va[0], 0.f); va[1] = fmaxf(va[1], 0.f);
      va[2] = fmaxf(va[2], 0.f); va[3] = fmaxf(va[3], 0.f);
      __builtin_nontemporal_store(va, (f32x4*)(po0 + 16 * mt));
    }
    #pragma unroll
    for (int mt = 0; mt < 4; ++mt) {
      f32x4 vb = acc3b[mt];
      vb[0] = fmaxf(vb[0], 0.f); vb[1] = fmaxf(vb[1], 0.f);
      vb[2] = fmaxf(vb[2], 0.f); vb[3] = fmaxf(vb[3], 0.f);
      __builtin_nontemporal_store(vb, (f32x4*)(po1 + 16 * mt));
    }
  }
}

extern "C" void kernel_launch(void* const* d_in, const int* in_sizes, int n_in,
                              void* d_out, int out_size, void* d_ws, size_t ws_size,
                              hipStream_t stream) {
  const float* x  = (const float*)d_in[0];
  const float* w1 = (const float*)d_in[1];
  const float* w2 = (const float*)d_in[2];
  const float* w3 = (const float*)d_in[3];
  float* out = (float*)d_out;
  (void)in_sizes; (void)n_in; (void)out_size; (void)d_ws; (void)ws_size;
  DeepBlockDense_kernel<<<dim3(NG), dim3(512), 0, stream>>>(x, w1, w2, w3, out);
}

// Round 16
// 70.805 us; speedup vs baseline: 1.2739x; 1.0049x over previous
//
#include <hip/hip_runtime.h>

#define NG  512
#define GW  32768    // G*W
#define GH3 32768    // G*H3

typedef __attribute__((ext_vector_type(8))) short bf16x8;
typedef __attribute__((ext_vector_type(4))) float f32x4;
typedef __attribute__((ext_vector_type(4))) unsigned int u32x4;
typedef __attribute__((ext_vector_type(2))) __bf16 bf16x2;

union frag_u { u32x4 u; bf16x8 h; };

#define MFMA __builtin_amdgcn_mfma_f32_16x16x32_bf16

// two floats -> packed bf16 pair (RNE); clang fuses into v_cvt_pk_bf16_f32
__device__ __forceinline__ unsigned cvt2bf(float a, float b) {
  bf16x2 v = {(__bf16)a, (__bf16)b};
  return __builtin_bit_cast(unsigned, v);
}

// (E,O) packed D-words -> B-operand words via half/row swaps.
__device__ __forceinline__ void permswap(unsigned &e, unsigned &o) {
  asm volatile("s_nop 1\n\t"
               "v_permlane32_swap_b32 %0, %1\n\t"
               "s_nop 1\n\t"
               "v_permlane16_swap_b32 %0, %1\n\t"
               "s_nop 1"
               : "+v"(e), "+v"(o));
}

// One B-fragment from an acc-tile pair, with relu.
__device__ __forceinline__ void mk_bfrag1(f32x4 e, f32x4 o, frag_u &bf) {
  unsigned E0 = cvt2bf(fmaxf(e[0], 0.f), fmaxf(e[1], 0.f));
  unsigned E1 = cvt2bf(fmaxf(e[2], 0.f), fmaxf(e[3], 0.f));
  unsigned O0 = cvt2bf(fmaxf(o[0], 0.f), fmaxf(o[1], 0.f));
  unsigned O1 = cvt2bf(fmaxf(o[2], 0.f), fmaxf(o[3], 0.f));
  permswap(E0, O0);   // -> w0, w2
  permswap(E1, O1);   // -> w1, w3
  bf.u = (u32x4){E0, E1, O0, O1};
}

// Stage W[g] ([K][H] fp32 row-major) into LDS frag-major (conflict-free):
// frag (mt,kc) = 1024 contiguous bytes, lane slot at lane*16. 512-thread
// cooperative (each half-block stages its own group).
template<int K, int H>
__device__ __forceinline__ void stage_frag(const float* __restrict__ gsrc,
                                           char* ldsBase, int tid) {
  constexpr int KC = K / 32;
  constexpr int NELEM = (K / 8) * H;
  #pragma unroll
  for (int lin = tid; lin < NELEM; lin += 512) {
    const int h  = lin & (H - 1);
    const int kb = lin / H;
    const float* p = gsrc + h + (size_t)(8 * kb) * H;
    unsigned w0 = cvt2bf(p[0 * H], p[1 * H]);
    unsigned w1 = cvt2bf(p[2 * H], p[3 * H]);
    unsigned w2 = cvt2bf(p[4 * H], p[5 * H]);
    unsigned w3 = cvt2bf(p[6 * H], p[7 * H]);
    const int mt = h >> 4, bl = h & 15, kc = kb >> 2, bq = kb & 3;
    const int byteoff = ((mt * KC + kc) * 64 + bq * 16 + bl) * 16;
    *(u32x4*)(ldsBase + byteoff) = (u32x4){w0, w1, w2, w3};
  }
}

// Raw x row segment: 4 f32x4 (k-octets bq and bq+4). PLAIN loads.
__device__ __forceinline__ void ld_raw(const float* px, f32x4* d) {
  d[0] = *(const f32x4*)(px + 0);
  d[1] = *(const f32x4*)(px + 4);
  d[2] = *(const f32x4*)(px + 32);
  d[3] = *(const f32x4*)(px + 36);
}

__device__ __forceinline__ void cvt_b1(const f32x4* d, frag_u* b1) {
  b1[0].u = (u32x4){cvt2bf(d[0][0], d[0][1]), cvt2bf(d[0][2], d[0][3]),
                    cvt2bf(d[1][0], d[1][1]), cvt2bf(d[1][2], d[1][3])};
  b1[1].u = (u32x4){cvt2bf(d[2][0], d[2][1]), cvt2bf(d[2][2], d[2][3]),
                    cvt2bf(d[3][0], d[3][1]), cvt2bf(d[3][2], d[3][3])};
}

// 2 GROUPS PER BLOCK: 256 blocks x 1024 thr, 128 KB LDS, 1 blk/CU =
// 16 waves/CU = 4/SIMD (same occupancy as r8). Each wave computes BOTH
// groups for its 16 rows (a = g0, b = g1 -> same dual-chain ILP as the
// old 2-row-tile split) and stores a CONTIGUOUS 512-B span per row,
// targeting the NT partial-granule write inflation (175 vs 131 MB).
__global__ __launch_bounds__(1024, 4)
void DeepBlockDense_kernel(const float* __restrict__ x,
                           const float* __restrict__ w1,
                           const float* __restrict__ w2,
                           const float* __restrict__ w3,
                           float* __restrict__ out) {
  __shared__ __align__(16) char smem[131072];
  // XCD-chunked swizzle on group-pairs: XCD k owns gp [32k,32k+32)
  // -> g span [64k,64k+64), contiguous 16-KB x/out row spans per XCD.
  const int gp   = ((blockIdx.x & 7) << 5) + (blockIdx.x >> 3);  // 0..255
  const int g0   = gp * 2;
  const int tid  = threadIdx.x;
  const int lane = tid & 63;
  const int wid  = tid >> 6;     // 0..15
  const int bq   = lane >> 4;

  // T14: issue t=0 x-loads (both groups) BEFORE staging
  const size_t row0 = (size_t)(wid * 16 + (lane & 15));
  f32x4 xra[4], xrb[4];
  ld_raw(x + row0 * GW + g0 * 64 +  0 + 8 * bq, xra);
  ld_raw(x + row0 * GW + g0 * 64 + 64 + 8 * bq, xrb);

  // staging: half-block per group (t512 = 512-thread cooperative)
  {
    const int half = tid >> 9;           // 0 or 1
    const int t512 = tid & 511;
    char* base = smem + (half << 16);
    const size_t gg = (size_t)(g0 + half);
    stage_frag<64 , 128>(w1 + gg * (64 * 128) , base        , t512);
    stage_frag<128, 128>(w2 + gg * (128 * 128), base + 16384, t512);
    stage_frag<128, 64 >(w3 + gg * (128 * 64) , base + 49152, t512);
  }
  __syncthreads();

  const char* aBase0 = smem + lane * 16;           // g0 frags
  const char* aBase1 = smem + 65536 + lane * 16;   // g1 frags

  #pragma unroll 1
  for (int t = 0; t < 4; ++t) {
    const size_t r = (size_t)(t * 256 + wid * 16 + (lane & 15));

    // ---- consume prefetched x; issue next iter's loads
    frag_u b1a[2], b1b[2];
    cvt_b1(xra, b1a);
    cvt_b1(xrb, b1b);
    if (t < 3) {
      const size_t rn = r + 256;
      ld_raw(x + rn * GW + g0 * 64 +  0 + 8 * bq, xra);
      ld_raw(x + rn * GW + g0 * 64 + 64 + 8 * bq, xrb);
    }

    // ---- layer 1 (M=128,K=64) x 2 groups, b2-frag build per mt-pair
    frag_u b2a[4], b2b[4];
    #pragma unroll
    for (int pr = 0; pr < 4; ++pr) {
      f32x4 ea = {}, oa = {}, eb = {}, ob = {};
      #pragma unroll
      for (int kc = 0; kc < 2; ++kc) {
        const int oe = 1024 * ((2 * pr    ) * 2 + kc);
        const int oo = 1024 * ((2 * pr + 1) * 2 + kc);
        frag_u ae0, ao0, ae1, ao1;
        ae0.u = *(const u32x4*)(aBase0 + oe);
        ao0.u = *(const u32x4*)(aBase0 + oo);
        ae1.u = *(const u32x4*)(aBase1 + oe);
        ao1.u = *(const u32x4*)(aBase1 + oo);
        ea = MFMA(ae0.h, b1a[kc].h, ea, 0, 0, 0);
        eb = MFMA(ae1.h, b1b[kc].h, eb, 0, 0, 0);
        oa = MFMA(ao0.h, b1a[kc].h, oa, 0, 0, 0);
        ob = MFMA(ao1.h, b1b[kc].h, ob, 0, 0, 0);
      }
      mk_bfrag1(ea, oa, b2a[pr]);
      mk_bfrag1(eb, ob, b2b[pr]);
    }

    // ---- layer 2 (M=128,K=128) + layer 3 (M=64,K=128) x 2 groups
    f32x4 acc3a[4] = {}, acc3b[4] = {};
    #pragma unroll
    for (int pr = 0; pr < 4; ++pr) {
      f32x4 ea = {}, oa = {}, eb = {}, ob = {};
      #pragma unroll
      for (int kc = 0; kc < 4; ++kc) {
        const int oe = 16384 + 1024 * ((2 * pr    ) * 4 + kc);
        const int oo = 16384 + 1024 * ((2 * pr + 1) * 4 + kc);
        frag_u ae0, ao0, ae1, ao1;
        ae0.u = *(const u32x4*)(aBase0 + oe);
        ao0.u = *(const u32x4*)(aBase0 + oo);
        ae1.u = *(const u32x4*)(aBase1 + oe);
        ao1.u = *(const u32x4*)(aBase1 + oo);
        ea = MFMA(ae0.h, b2a[kc].h, ea, 0, 0, 0);
        eb = MFMA(ae1.h, b2b[kc].h, eb, 0, 0, 0);
        oa = MFMA(ao0.h, b2a[kc].h, oa, 0, 0, 0);
        ob = MFMA(ao1.h, b2b[kc].h, ob, 0, 0, 0);
      }
      frag_u b3a, b3b;
      mk_bfrag1(ea, oa, b3a);
      mk_bfrag1(eb, ob, b3b);
      #pragma unroll
      for (int mt = 0; mt < 4; ++mt) {
        const int o3 = 49152 + 1024 * (mt * 4 + pr);
        frag_u a0, a1;
        a0.u = *(const u32x4*)(aBase0 + o3);
        a1.u = *(const u32x4*)(aBase1 + o3);
        acc3a[mt] = MFMA(a0.h, b3a.h, acc3a[mt], 0, 0, 0);
        acc3b[mt] = MFMA(a1.h, b3b.h, acc3b[mt], 0, 0, 0);
      }
    }

    // ---- relu + NT stores: per row, 8 back-to-back dwordx4 covering
    // a CONTIGUOUS 512-B span (g0's 256 B then g1's 256 B) -> granule-
    // complete writes from a single wave.
    float* po = out + r * GH3 + g0 * 64 + 4 * bq;
    #pragma unroll
    for (int mt = 0; mt < 4; ++mt) {
      f32x4 va = acc3a[mt];
      va[0] = fmaxf(va[0], 0.f); va[1] = fmaxf(va[1], 0.f);
      va[2] = fmaxf(va[2], 0.f); va[3] = fmaxf(va[3], 0.f);
      __builtin_nontemporal_store(va, (f32x4*)(po + 16 * mt));
    }
    #pragma unroll
    for (int mt = 0; mt < 4; ++mt) {
      f32x4 vb = acc3b[mt];
      vb[0] = fmaxf(vb[0], 0.f); vb[1] = fmaxf(vb[1], 0.f);
      vb[2] = fmaxf(vb[2], 0.f); vb[3] = fmaxf(vb[3], 0.f);
      __builtin_nontemporal_store(vb, (f32x4*)(po + 64 + 16 * mt));
    }
  }
}

extern "C" void kernel_launch(void* const* d_in, const int* in_sizes, int n_in,
                              void* d_out, int out_size, void* d_ws, size_t ws_size,
                              hipStream_t stream) {
  const float* x  = (const float*)d_in[0];
  const float* w1 = (const float*)d_in[1];
  const float* w2 = (const float*)d_in[2];
  const float* w3 = (const float*)d_in[3];
  float* out = (float*)d_out;
  (void)in_sizes; (void)n_in; (void)out_size; (void)d_ws; (void)ws_size;
  DeepBlockDense_kernel<<<dim3(NG / 2), dim3(1024), 0, stream>>>(x, w1, w2, w3, out);
}